// Round 14
// baseline (124.059 us; speedup 1.0000x reference)
//
#include <hip/hip_runtime.h>
#include <hip/hip_bf16.h>
#include <math.h>

#define BDIM 32
#define TDIM 1025
#define DDIM 768
#define GRIDW 32
#define TPATCH 1024
#define SCALE 8.0f
#define EPSLN 1e-5f
#define NROW (BDIM * TDIM)   // 32800 = 1025 * 32
#define VTLD 1088            // vT row stride (elements, 16B-aligned)
#define LDP  72              // LDS row stride for attn tiles
#define LDA  772             // As row stride (elems): slot step 2 -> conflict-free
#define LDB  40              // Bs row stride (elems): slot step 20 -> 2-way (free)
#define NTILES 17

typedef __attribute__((ext_vector_type(8))) short short8v;   // 8 bf16 (4 VGPRs)
typedef __attribute__((ext_vector_type(4))) float f32x4;     // MFMA C/D frag

__device__ __forceinline__ unsigned short f2bf(float f) {
    unsigned int u = __float_as_uint(f);
    u += 0x7FFFu + ((u >> 16) & 1u);      // round-to-nearest-even
    return (unsigned short)(u >> 16);
}

// Raw workgroup barrier (no vmcnt(0) drain) — attn only.
__device__ __forceinline__ void wg_barrier() {
    asm volatile("s_waitcnt lgkmcnt(0)" ::: "memory");
    __builtin_amdgcn_s_barrier();
    __builtin_amdgcn_sched_barrier(0);
}

// ---- 16-lane DPP reductions (attn only) ----
template<int CTRL>
__device__ __forceinline__ float dpp_f(float x) {
    return __int_as_float(__builtin_amdgcn_update_dpp(
        __float_as_int(x), __float_as_int(x), CTRL, 0xF, 0xF, true));
}
__device__ __forceinline__ float red16_max(float x) {
    x = fmaxf(x, dpp_f<0xB1>(x));
    x = fmaxf(x, dpp_f<0x4E>(x));
    x = fmaxf(x, dpp_f<0x124>(x));
    x = fmaxf(x, dpp_f<0x128>(x));
    return x;
}
__device__ __forceinline__ float red16_sum(float x) {
    x += dpp_f<0xB1>(x);
    x += dpp_f<0x4E>(x);
    x += dpp_f<0x124>(x);
    x += dpp_f<0x128>(x);
    return x;
}

// ---------------------------------------------------------------------------
// Kernel 0: W -> bf16, K-STEP-TILED: wTt[ks][c][kk], ks=k/32, kk=k%32.
// Each k-step's B tile (192x32 bf16 = 12 KB) is contiguous.
// ---------------------------------------------------------------------------
__global__ __launch_bounds__(256) void prep_w_kernel(
    const float* __restrict__ Wq, const float* __restrict__ Wk,
    const float* __restrict__ Wv, unsigned short* __restrict__ wTt)
{
    const int c = blockIdx.x;                  // 0..191
    const float* W = (c < 64) ? Wq : (c < 128) ? Wk : Wv;
    const int cc = c & 63;
    for (int k = threadIdx.x; k < DDIM; k += 256) {
        int ks = k >> 5, kk = k & 31;
        wTt[(size_t)ks * 6144 + c * 32 + kk] = f2bf(W[(size_t)k * 64 + cc]);
    }
}

// ---------------------------------------------------------------------------
// Kernel 1: MFMA QKV projection + fused LN + heads — SEQUENTIAL-A edition.
// 1025 blocks x 256 thr (4 waves). Block = 32 rows (a CONTIGUOUS 96 KB span
// of x). Phase A: stream the span linearly (coalesced float4, 2-deep group
// pipeline), convert fp32->bf16, park in LDS As[32][772]. Phase B: 24 K-steps
// reading A from LDS; B dbuf reg-staged from contiguous wTt tiles.
// Wave roles: rh=wv&1 (rows 0-15/16-31), nh=wv>>1 (frags {q0-3,v8,9} vs
// {k4-7,v10,11}) — q-LN wholly in nh=0, k-LN wholly in nh=1.
// LDS 78.5 KB -> 2 blocks/CU.
// ---------------------------------------------------------------------------
__global__ __launch_bounds__(256) void qkv_tile_kernel(
    const float* __restrict__ x, const unsigned short* __restrict__ wTt,
    const float* __restrict__ gq, const float* __restrict__ bq,
    const float* __restrict__ gk, const float* __restrict__ bk,
    const float* __restrict__ Wsig, const float* __restrict__ bsig,
    const float* __restrict__ Wa, const float* __restrict__ ba,
    unsigned short* __restrict__ qb, unsigned short* __restrict__ kb,
    unsigned short* __restrict__ vb,
    float* __restrict__ a8, float* __restrict__ isx, float* __restrict__ isy)
{
    __shared__ unsigned short As[32][LDA];       // 49.4 KB, bf16
    __shared__ unsigned short Bs[2][192][LDB];   // 30.7 KB

    const int t  = threadIdx.x;
    const int wv = t >> 6;
    const int rh = wv & 1;        // row half
    const int nh = wv >> 1;       // frag-set half (0: q+vlow, 1: k+vhigh)
    const int ln = t & 63;
    const int lq = ln >> 4;
    const int lr = ln & 15;
    const int tok0 = blockIdx.x * 32;   // flat row; 1025*32 == NROW exactly

    // ---- Phase A: sequential stream of the block's 96 KB x-span ----
    {
        const float4* xsp = (const float4*)(x + (size_t)tok0 * DDIM);
        float4 ga[6], gb[6];
#define ALOADG(R, G)                                                           \
        _Pragma("unroll") for (int j = 0; j < 6; ++j)                          \
            R[j] = xsp[t + 256 * ((G) * 6 + j)];
#define APROCG(R, G)                                                           \
        _Pragma("unroll") for (int j = 0; j < 6; ++j) {                        \
            int f0 = (t + 256 * ((G) * 6 + j)) * 4;                            \
            int row = f0 / DDIM;                                               \
            int col = f0 - row * DDIM;                                         \
            ushort4 pk;                                                        \
            pk.x = f2bf(R[j].x); pk.y = f2bf(R[j].y);                          \
            pk.z = f2bf(R[j].z); pk.w = f2bf(R[j].w);                          \
            *(ushort4*)&As[row][col] = pk;                                     \
        }
        ALOADG(ga, 0);
        ALOADG(gb, 1);
        APROCG(ga, 0);
        ALOADG(ga, 2);
        APROCG(gb, 1);
        ALOADG(gb, 3);
        APROCG(ga, 2);
        APROCG(gb, 3);
#undef ALOADG
#undef APROCG
    }

    // ---- B staging maps (reg-staged dbuf from contiguous 12 KB tiles) ----
    short8v rb[3];
#define BLOAD(KS)                                                              \
    _Pragma("unroll") for (int j = 0; j < 3; ++j)                              \
        rb[j] = *(const short8v*)&wTt[(size_t)(KS) * 6144 +                    \
                                      (size_t)(t + 256 * j) * 8];
#define BSTORE(BUF)                                                            \
    _Pragma("unroll") for (int j = 0; j < 3; ++j) {                            \
        int idx = t + 256 * j;                                                 \
        *(short8v*)&Bs[BUF][idx >> 2][(idx & 3) * 8] = rb[j];                  \
    }

    f32x4 acc[6];
#pragma unroll
    for (int j = 0; j < 6; ++j) acc[j] = (f32x4){0.f, 0.f, 0.f, 0.f};

    BLOAD(0);
    BSTORE(0);
    __syncthreads();     // As + Bs[0] visible

    const int arow = rh * 16 + lr;
    for (int ks = 0; ks < 24; ++ks) {
        const int buf = ks & 1;
        if (ks + 1 < 24) BLOAD(ks + 1);            // L2-resident loads
        short8v af = *(const short8v*)&As[arow][ks * 32 + lq * 8];
#pragma unroll
        for (int j = 0; j < 6; ++j) {
            int frag = (j < 4) ? (nh * 4 + j) : (8 + nh * 2 + (j - 4));
            short8v bf = *(const short8v*)&Bs[buf][16 * frag + lr][lq * 8];
            acc[j] = __builtin_amdgcn_mfma_f32_16x16x32_bf16(af, bf, acc[j], 0, 0, 0);
        }
        if (ks + 1 < 24) BSTORE(buf ^ 1);          // waits its own loads only
        __syncthreads();
    }
#undef BLOAD
#undef BSTORE

    // ---- epilogue: per-role LN + head + writes ----
    float gv[4], bv[4], wav[4], ws0[4], ws1[4];
#pragma unroll
    for (int ni = 0; ni < 4; ++ni) {
        int c = lr + 16 * ni;
        if (nh == 0) {
            gv[ni] = gq[c]; bv[ni] = bq[c];
            wav[ni] = Wa[c];
            ws0[ni] = Wsig[2 * c];
            ws1[ni] = Wsig[2 * c + 1];
        } else {
            gv[ni] = gk[c]; bv[ni] = bk[c];
            wav[ni] = 0.f; ws0[ni] = 0.f; ws1[ni] = 0.f;
        }
    }
    const float ba0 = ba[0], bs0 = bsig[0], bs1 = bsig[1];

#pragma unroll
    for (int reg = 0; reg < 4; ++reg) {
        const int tokr = tok0 + rh * 16 + lq * 4 + reg;   // always < NROW

        // LN over this wave's 4 proj frags (q for nh=0, k for nh=1)
        float s1 = 0.f, s2 = 0.f;
#pragma unroll
        for (int ni = 0; ni < 4; ++ni) {
            float v = acc[ni][reg];
            s1 += v; s2 += v * v;
        }
#pragma unroll
        for (int off = 1; off < 16; off <<= 1) {
            s1 += __shfl_xor(s1, off);
            s2 += __shfl_xor(s2, off);
        }
        float mean = s1 * (1.f / 64.f);
        float var  = s2 * (1.f / 64.f) - mean * mean;
        float rstd = rsqrtf(var + EPSLN);
        float xn[4];
#pragma unroll
        for (int ni = 0; ni < 4; ++ni)
            xn[ni] = (acc[ni][reg] - mean) * rstd * gv[ni] + bv[ni];

        size_t base = (size_t)tokr * 64;
        unsigned short* dst = (nh == 0) ? qb : kb;
#pragma unroll
        for (int ni = 0; ni < 4; ++ni)
            dst[base + lr + 16 * ni] = f2bf(xn[ni]);
        // v columns: frags 8+2nh, 9+2nh -> cols lr+32nh, lr+32nh+16
        vb[base + lr + 32 * nh]      = f2bf(acc[4][reg]);
        vb[base + lr + 32 * nh + 16] = f2bf(acc[5][reg]);

        if (nh == 0) {
            float da = 0.f, d0 = 0.f, d1 = 0.f;
#pragma unroll
            for (int ni = 0; ni < 4; ++ni) {
                da += xn[ni] * wav[ni];
                d0 += xn[ni] * ws0[ni];
                d1 += xn[ni] * ws1[ni];
            }
#pragma unroll
            for (int off = 1; off < 16; off <<= 1) {
                da += __shfl_xor(da, off);
                d0 += __shfl_xor(d0, off);
                d1 += __shfl_xor(d1, off);
            }
            if (lr == 0) {
                int bidx = tokr / TDIM;
                int ti   = tokr - bidx * TDIM;
                if (ti >= 1) {
                    int p = bidx * TPATCH + ti - 1;
                    float av = da + ba0;
                    float sp = (av > 20.f) ? av : log1pf(__expf(av));
                    a8[p] = sp * (1.f / SCALE);
                    float sx = 1.f / (1.f + __expf(-(d0 + bs0)));
                    float sy = 1.f / (1.f + __expf(-(d1 + bs1)));
                    isx[p] = 0.5f / (sx * sx);
                    isy[p] = 0.5f / (sy * sy);
                }
            }
        }
    }
}

// ---------------------------------------------------------------------------
// Kernel 1b: vb [token][dh] -> vT [b][dh][token] via LDS transpose.
// ---------------------------------------------------------------------------
__global__ __launch_bounds__(256) void vtrans_kernel(
    const unsigned short* __restrict__ vb, unsigned short* __restrict__ vT)
{
    __shared__ unsigned short tile[64][LDP];   // [dh][token]
    const int t  = threadIdx.x;
    const int bb = blockIdx.y;
    const int t0 = blockIdx.x * 64;

#pragma unroll
    for (int it = 0; it < 2; ++it) {
        int lin = t + it * 256;
        int tok = lin >> 3;
        int d0  = (lin & 7) * 8;
        short8v v8 = {0, 0, 0, 0, 0, 0, 0, 0};
        if (t0 + tok < TDIM)
            v8 = *(const short8v*)&vb[((size_t)bb * TDIM + t0 + tok) * 64 + d0];
        union { short8v v; unsigned short s[8]; } u; u.v = v8;
#pragma unroll
        for (int j = 0; j < 8; ++j) tile[d0 + j][tok] = u.s[j];
    }
    __syncthreads();

    const int dh = t >> 2;
    const int ch = t & 3;
    short8v o0 = *(const short8v*)&tile[dh][ch * 16];
    short8v o1 = *(const short8v*)&tile[dh][ch * 16 + 8];
    size_t dst = ((size_t)bb * 64 + dh) * VTLD + t0 + ch * 16;
    *(short8v*)&vT[dst]     = o0;
    *(short8v*)&vT[dst + 8] = o1;
}

// ---------------------------------------------------------------------------
// Kernel 2: MFMA flash attention (measured-good: raw barriers, dbuf K/V,
// issue-early/write-late, DPP softmax, Q direct from global). Unchanged.
// ---------------------------------------------------------------------------
__global__ __launch_bounds__(256) void attn_mfma_kernel(
    const unsigned short* __restrict__ qb, const unsigned short* __restrict__ kb,
    const unsigned short* __restrict__ vT,
    const float* __restrict__ a8, const float* __restrict__ isx,
    const float* __restrict__ isy, float* __restrict__ out)
{
    __shared__ unsigned short Ks[2][64][LDP];
    __shared__ unsigned short Vt[2][64][LDP];   // [dh][key]
    __shared__ unsigned short Pt[4][16][LDP];   // per-wave [q][key]

    const int t  = threadIdx.x;
    const int wv = t >> 6;
    const int ln = t & 63;
    const int lq = ln >> 4;
    const int lr = ln & 15;
    const int bb = blockIdx.y;
    const int q0 = blockIdx.x * 64;

    const int qrow = min(q0 + wv * 16 + lr, TDIM - 1);
    const size_t qbase = ((size_t)bb * TDIM + qrow) * 64;
    const short8v aq0 = *(const short8v*)&qb[qbase + lq * 8];
    const short8v aq1 = *(const short8v*)&qb[qbase + 32 + lq * 8];

    float a8q[4], sxq[4], syq[4], qpy[4], qpx[4];
    bool  hasS[4];
#pragma unroll
    for (int reg = 0; reg < 4; ++reg) {
        int qg = q0 + wv * 16 + lq * 4 + reg;
        hasS[reg] = false;
        a8q[reg] = 0.f; sxq[reg] = 0.f; syq[reg] = 0.f; qpy[reg] = 0.f; qpx[reg] = 0.f;
        if (qg >= 1 && qg < TDIM) {
            int qp = qg - 1;
            hasS[reg] = true;
            a8q[reg] = a8 [bb * TPATCH + qp];
            sxq[reg] = isx[bb * TPATCH + qp];
            syq[reg] = isy[bb * TPATCH + qp];
            qpy[reg] = (float)(qp >> 5);
            qpx[reg] = (float)(qp & 31);
        }
    }

    float m[4]  = {-1e30f, -1e30f, -1e30f, -1e30f};
    float l[4]  = {0.f, 0.f, 0.f, 0.f};
    f32x4 oacc[4];
#pragma unroll
    for (int ni = 0; ni < 4; ++ni) oacc[ni] = (f32x4){0.f, 0.f, 0.f, 0.f};

    const int sk_row = t >> 3;
    const int sk_d0  = (t & 7) * 8;
    short8v rk[2], rv[2];

#define ALOAD(KT0)                                                             \
    do {                                                                       \
        _Pragma("unroll") for (int it = 0; it < 2; ++it) {                     \
            int key = sk_row + 32 * it;                                        \
            int kg  = (KT0) + key;                                             \
            rk[it] = (kg < TDIM)                                               \
                ? *(const short8v*)&kb[((size_t)bb * TDIM + kg) * 64 + sk_d0]  \
                : (short8v){0, 0, 0, 0, 0, 0, 0, 0};                           \
            rv[it] = *(const short8v*)&vT[((size_t)bb * 64 + key) * VTLD +     \
                                          (KT0) + sk_d0];                      \
        }                                                                      \
    } while (0)

#define ASTORE(BUF)                                                            \
    do {                                                                       \
        _Pragma("unroll") for (int it = 0; it < 2; ++it) {                     \
            *(short8v*)&Ks[BUF][sk_row + 32 * it][sk_d0] = rk[it];             \
            *(short8v*)&Vt[BUF][sk_row + 32 * it][sk_d0] = rv[it];             \
        }                                                                      \
    } while (0)

    ALOAD(0);
    ASTORE(0);
    wg_barrier();

    for (int tile = 0; tile < NTILES; ++tile) {
        const int kt0 = tile * 64;
        const int buf = tile & 1;
        if (tile + 1 < NTILES) ALOAD(kt0 + 64);

        f32x4 sac[4];
#pragma unroll
        for (int ni = 0; ni < 4; ++ni) sac[ni] = (f32x4){0.f, 0.f, 0.f, 0.f};
#pragma unroll
        for (int ni = 0; ni < 4; ++ni) {
            short8v b0 = *(const short8v*)&Ks[buf][16 * ni + lr][lq * 8];
            short8v b1 = *(const short8v*)&Ks[buf][16 * ni + lr][32 + lq * 8];
            sac[ni] = __builtin_amdgcn_mfma_f32_16x16x32_bf16(aq0, b0, sac[ni], 0, 0, 0);
            sac[ni] = __builtin_amdgcn_mfma_f32_16x16x32_bf16(aq1, b1, sac[ni], 0, 0, 0);
        }

#pragma unroll
        for (int ni = 0; ni < 4; ++ni) {
            int key = kt0 + 16 * ni + lr;
            int kp  = key - 1;
            float ky = (float)(kp >> 5);
            float kx = (float)(kp & 31);
            bool kvalid = (key >= 1) && (key < TDIM);
#pragma unroll
            for (int reg = 0; reg < 4; ++reg) {
                float z = sac[ni][reg] * (1.f / SCALE);
                if (kvalid && hasS[reg]) {
                    float dy = qpy[reg] - ky;
                    float dx = qpx[reg] - kx;
                    z += a8q[reg] * __expf(-(dx * dx * sxq[reg] + dy * dy * syq[reg]));
                }
                if (key >= TDIM) z = -1e30f;
                sac[ni][reg] = z;
            }
        }

        float scf[4];
#pragma unroll
        for (int reg = 0; reg < 4; ++reg) {
            float mx = fmaxf(fmaxf(sac[0][reg], sac[1][reg]),
                             fmaxf(sac[2][reg], sac[3][reg]));
            mx = red16_max(mx);
            float mn = fmaxf(m[reg], mx);
            scf[reg] = __expf(m[reg] - mn);
            m[reg] = mn;
            float ts = 0.f;
#pragma unroll
            for (int ni = 0; ni < 4; ++ni) {
                float pp = __expf(sac[ni][reg] - mn);
                sac[ni][reg] = pp;
                ts += pp;
            }
            ts = red16_sum(ts);
            l[reg] = l[reg] * scf[reg] + ts;
        }
#pragma unroll
        for (int ni = 0; ni < 4; ++ni)
#pragma unroll
            for (int reg = 0; reg < 4; ++reg)
                oacc[ni][reg] *= scf[reg];

#pragma unroll
        for (int ni = 0; ni < 4; ++ni)
#pragma unroll
            for (int reg = 0; reg < 4; ++reg)
                Pt[wv][lq * 4 + reg][16 * ni + lr] = f2bf(sac[ni][reg]);

#pragma unroll
        for (int ks = 0; ks < 2; ++ks) {
            short8v pa = *(const short8v*)&Pt[wv][lr][ks * 32 + lq * 8];
#pragma unroll
            for (int ni = 0; ni < 4; ++ni) {
                short8v bv = *(const short8v*)&Vt[buf][16 * ni + lr][ks * 32 + lq * 8];
                oacc[ni] = __builtin_amdgcn_mfma_f32_16x16x32_bf16(pa, bv, oacc[ni], 0, 0, 0);
            }
        }

        if (tile + 1 < NTILES) ASTORE(buf ^ 1);
        wg_barrier();
    }
#undef ALOAD
#undef ASTORE

#pragma unroll
    for (int reg = 0; reg < 4; ++reg) {
        int qg = q0 + wv * 16 + lq * 4 + reg;
        if (qg < TDIM) {
            float rl = 1.f / l[reg];
#pragma unroll
            for (int ni = 0; ni < 4; ++ni)
                out[((size_t)bb * TDIM + qg) * 64 + 16 * ni + lr] = oacc[ni][reg] * rl;
        }
    }
}

extern "C" void kernel_launch(void* const* d_in, const int* in_sizes, int n_in,
                              void* d_out, int out_size, void* d_ws, size_t ws_size,
                              hipStream_t stream)
{
    const float* x    = (const float*)d_in[0];
    const float* Wq   = (const float*)d_in[1];
    const float* Wk   = (const float*)d_in[2];
    const float* Wv   = (const float*)d_in[3];
    const float* gq   = (const float*)d_in[4];
    const float* bq   = (const float*)d_in[5];
    const float* gk   = (const float*)d_in[6];
    const float* bk   = (const float*)d_in[7];
    const float* Wsig = (const float*)d_in[8];
    const float* bsig = (const float*)d_in[9];
    const float* Wa   = (const float*)d_in[10];
    const float* ba   = (const float*)d_in[11];
    float* out = (float*)d_out;

    // ---- workspace layout ----
    char* w = (char*)d_ws;
    const size_t NQ = (size_t)NROW * 64;
    unsigned short* qb = (unsigned short*)w;   w += NQ * 2;
    unsigned short* kb = (unsigned short*)w;   w += NQ * 2;
    unsigned short* vb = (unsigned short*)w;   w += NQ * 2;
    unsigned short* vT = (unsigned short*)w;   w += (size_t)BDIM * 64 * VTLD * 2;
    float* a8  = (float*)w;                    w += (size_t)BDIM * TPATCH * 4;
    float* isx = (float*)w;                    w += (size_t)BDIM * TPATCH * 4;
    float* isy = (float*)w;                    w += (size_t)BDIM * TPATCH * 4;
    unsigned short* wTt = (unsigned short*)w;  w += (size_t)192 * DDIM * 2;

    hipLaunchKernelGGL(prep_w_kernel, dim3(192), dim3(256), 0, stream,
                       Wq, Wk, Wv, wTt);

    const int nblk1 = NROW / 32;   // 1025 blocks of 32 rows (exact cover)
    hipLaunchKernelGGL(qkv_tile_kernel, dim3(nblk1), dim3(256), 0, stream,
                       x, wTt, gq, bq, gk, bk, Wsig, bsig, Wa, ba,
                       qb, kb, vb, a8, isx, isy);

    hipLaunchKernelGGL(vtrans_kernel, dim3(17, BDIM), dim3(256), 0, stream,
                       vb, vT);

    hipLaunchKernelGGL(attn_mfma_kernel, dim3(17, BDIM), dim3(256), 0, stream,
                       qb, kb, vT, a8, isx, isy, out);
}

// Round 15
// 110.596 us; speedup vs baseline: 1.1217x; 1.1217x over previous
//
#include <hip/hip_runtime.h>
#include <hip/hip_bf16.h>
#include <math.h>

#define BDIM 32
#define TDIM 1025
#define DDIM 768
#define GRIDW 32
#define TPATCH 1024
#define SCALE 8.0f
#define EPSLN 1e-5f
#define NROW (BDIM * TDIM)   // 32800 = 1025 * 32
#define VTLD 1088            // vT row stride (elements, 16B-aligned)
#define LDP  72              // LDS row stride for attn tiles
#define NTILES 17

typedef __attribute__((ext_vector_type(8))) short short8v;   // 8 bf16 (4 VGPRs)
typedef __attribute__((ext_vector_type(4))) float f32x4;     // MFMA C/D frag

__device__ __forceinline__ unsigned short f2bf(float f) {
    unsigned int u = __float_as_uint(f);
    u += 0x7FFFu + ((u >> 16) & 1u);      // round-to-nearest-even
    return (unsigned short)(u >> 16);
}

__device__ __forceinline__ short8v pack8(float4 a, float4 b) {
    union { short8v v; unsigned short s[8]; } u;
    u.s[0] = f2bf(a.x); u.s[1] = f2bf(a.y); u.s[2] = f2bf(a.z); u.s[3] = f2bf(a.w);
    u.s[4] = f2bf(b.x); u.s[5] = f2bf(b.y); u.s[6] = f2bf(b.z); u.s[7] = f2bf(b.w);
    return u.v;
}

// Async global->LDS DMA, 16B per lane. LDS dest is wave-uniform base
// (+ lane*16 added by HW); global src is per-lane.
#define GLOAD16(g, l)                                                          \
    __builtin_amdgcn_global_load_lds(                                          \
        (const __attribute__((address_space(1))) void*)(g),                    \
        (__attribute__((address_space(3))) void*)(l), 16, 0, 0)

// Raw workgroup barrier (no vmcnt(0) drain) — attn staging loop.
__device__ __forceinline__ void wg_barrier() {
    asm volatile("s_waitcnt lgkmcnt(0)" ::: "memory");
    __builtin_amdgcn_s_barrier();
    __builtin_amdgcn_sched_barrier(0);
}

// Counted-vmcnt barrier (T4): wait until <= N VMEM ops outstanding in THIS
// wave, then barrier. All waves arriving => tile's DMAs retired everywhere.
#define VBAR(N)                                                                \
    do {                                                                       \
        asm volatile("s_waitcnt vmcnt(" #N ")" ::: "memory");                  \
        __builtin_amdgcn_s_barrier();                                          \
        __builtin_amdgcn_sched_barrier(0);                                     \
    } while (0)

// ---- 16-lane DPP reductions (attn only) ----
template<int CTRL>
__device__ __forceinline__ float dpp_f(float x) {
    return __int_as_float(__builtin_amdgcn_update_dpp(
        __float_as_int(x), __float_as_int(x), CTRL, 0xF, 0xF, true));
}
__device__ __forceinline__ float red16_max(float x) {
    x = fmaxf(x, dpp_f<0xB1>(x));
    x = fmaxf(x, dpp_f<0x4E>(x));
    x = fmaxf(x, dpp_f<0x124>(x));
    x = fmaxf(x, dpp_f<0x128>(x));
    return x;
}
__device__ __forceinline__ float red16_sum(float x) {
    x += dpp_f<0xB1>(x);
    x += dpp_f<0x4E>(x);
    x += dpp_f<0x124>(x);
    x += dpp_f<0x128>(x);
    return x;
}

// ---------------------------------------------------------------------------
// Kernel 0: W -> bf16, K-STEP-TILED: wTt[ks][c][kk], ks=k/32, kk=k%32.
// Each k-step's B tile (192x32 bf16 = 12 KB) is contiguous.
// ---------------------------------------------------------------------------
__global__ __launch_bounds__(256) void prep_w_kernel(
    const float* __restrict__ Wq, const float* __restrict__ Wk,
    const float* __restrict__ Wv, unsigned short* __restrict__ wTt)
{
    const int c = blockIdx.x;                  // 0..191
    const float* W = (c < 64) ? Wq : (c < 128) ? Wk : Wv;
    const int cc = c & 63;
    for (int k = threadIdx.x; k < DDIM; k += 256) {
        int ks = k >> 5, kk = k & 31;
        wTt[(size_t)ks * 6144 + c * 32 + kk] = f2bf(W[(size_t)k * 64 + cc]);
    }
}

// ---------------------------------------------------------------------------
// Kernel 1: MFMA QKV projection + fused LN + heads — counted-vmcnt pipeline.
// 1025 blocks x 128 thr (2 waves x 16 rows); BM=32, BK=32, 24 steps.
// 3 LDS buffers, depth-2 DMA in flight. Per step:
//   vmcnt(8) [own 8 DMA ops of tile k done; 8 of tile k+1 stay in flight]
//   -> s_barrier -> COMPUTE(buf k) -> STAGE(tile k+2 -> buf (k+2)%3).
// No vmcnt(0), no lgkmcnt drain anywhere in the loop (T3/T4, m201 template).
// Buffer-reuse safe: all waves finish COMPUTE(k-1) before barrier(k), and
// stage(k+2) targets buf(k-1). LDS 48 KB -> 3 blocks/CU.
// ---------------------------------------------------------------------------
__global__ __launch_bounds__(128) void qkv_tile_kernel(
    const float* __restrict__ x, const unsigned short* __restrict__ wTt,
    const float* __restrict__ gq, const float* __restrict__ bq,
    const float* __restrict__ gk, const float* __restrict__ bk,
    const float* __restrict__ Wsig, const float* __restrict__ bsig,
    const float* __restrict__ Wa, const float* __restrict__ ba,
    unsigned short* __restrict__ qb, unsigned short* __restrict__ kb,
    unsigned short* __restrict__ vb,
    float* __restrict__ a8, float* __restrict__ isx, float* __restrict__ isy)
{
    __shared__ float          As[3][32][32];    // 3 x 4 KB, 128B rows
    __shared__ unsigned short Bs[3][192][32];   // 3 x 12 KB, 64B rows

    const int t  = threadIdx.x;
    const int wv = t >> 6;            // 0..1
    const int ln = t & 63;
    const int lq = ln >> 4;           // 0..3
    const int lr = ln & 15;           // 0..15
    const int tok0 = blockIdx.x * 32; // flat row; grid covers NROW exactly

    const char* xB = (const char*)x;

    // stage step KS into buffer BUF; exactly 8 DMA ops per wave.
    // A tile: XOR source-swizzle (seg ^= row&7) so frag reads are
    // conflict-free with linear DMA writes (inverse applied at read).
#define STAGE(BUF, KS)                                                         \
    do {                                                                       \
        const char* wB = (const char*)wTt + (size_t)(KS) * 12288;              \
        if (wv == 0) {                                                         \
            _Pragma("unroll") for (int c = 0; c < 4; ++c) {                    \
                int L = c * 1024 + ln * 16;                                    \
                int row = L >> 7;                                              \
                int seg = ((L >> 4) & 7) ^ (row & 7);                          \
                const char* g = xB + (size_t)(tok0 + row) * 3072 +             \
                                (size_t)(KS) * 128 + seg * 16;                 \
                GLOAD16(g, (char*)&As[BUF][0][0] + c * 1024);                  \
            }                                                                  \
            _Pragma("unroll") for (int c = 0; c < 4; ++c)                      \
                GLOAD16(wB + c * 1024 + ln * 16,                               \
                        (char*)&Bs[BUF][0][0] + c * 1024);                     \
        } else {                                                               \
            _Pragma("unroll") for (int c = 4; c < 12; ++c)                     \
                GLOAD16(wB + c * 1024 + ln * 16,                               \
                        (char*)&Bs[BUF][0][0] + c * 1024);                     \
        }                                                                      \
    } while (0)

#define COMPUTE(BUF)                                                           \
    do {                                                                       \
        const int arow = wv * 16 + lr;                                         \
        const int x7 = arow & 7;                                               \
        const char* ab = (const char*)&As[BUF][arow][0];                       \
        float4 f0 = *(const float4*)(ab + (((lq * 2)     ^ x7) * 16));         \
        float4 f1 = *(const float4*)(ab + (((lq * 2 + 1) ^ x7) * 16));         \
        short8v af = pack8(f0, f1);                                            \
        _Pragma("unroll") for (int ni = 0; ni < 12; ++ni) {                    \
            short8v bf = *(const short8v*)&Bs[BUF][16 * ni + lr][lq * 8];      \
            acc[ni] = __builtin_amdgcn_mfma_f32_16x16x32_bf16(af, bf,          \
                                                              acc[ni], 0, 0, 0); \
        }                                                                      \
    } while (0)

    f32x4 acc[12];
#pragma unroll
    for (int ni = 0; ni < 12; ++ni) acc[ni] = (f32x4){0.f, 0.f, 0.f, 0.f};

    // prologue: tiles 0 and 1 in flight (16 DMA ops/wave)
    STAGE(0, 0);
    STAGE(1, 1);

    for (int ks = 0; ks < 24; ++ks) {
        const int buf = ks % 3;
        if (ks < 23) VBAR(8);       // tile ks done; tile ks+1 stays in flight
        else         VBAR(0);       // last tile: nothing younger
        COMPUTE(buf);
        if (ks + 2 < 24) STAGE((ks + 2) % 3, ks + 2);
    }
#undef STAGE
#undef COMPUTE

    // ---- epilogue: LN(q), LN(k), alpha/sigma head, writes (shfl_xor) ----
    float gqv[4], bqv[4], gkv[4], bkv[4], wav[4], ws0[4], ws1[4];
#pragma unroll
    for (int ni = 0; ni < 4; ++ni) {
        int c = lr + 16 * ni;
        gqv[ni] = gq[c]; bqv[ni] = bq[c];
        gkv[ni] = gk[c]; bkv[ni] = bk[c];
        wav[ni] = Wa[c];
        ws0[ni] = Wsig[2 * c];
        ws1[ni] = Wsig[2 * c + 1];
    }
    const float ba0 = ba[0], bs0 = bsig[0], bs1 = bsig[1];

#pragma unroll
    for (int reg = 0; reg < 4; ++reg) {
        const int tokr = tok0 + wv * 16 + lq * 4 + reg;   // always < NROW

        float s1 = 0.f, s2 = 0.f;
#pragma unroll
        for (int ni = 0; ni < 4; ++ni) {
            float v = acc[ni][reg];
            s1 += v; s2 += v * v;
        }
#pragma unroll
        for (int off = 1; off < 16; off <<= 1) {
            s1 += __shfl_xor(s1, off);
            s2 += __shfl_xor(s2, off);
        }
        float mean = s1 * (1.f / 64.f);
        float var  = s2 * (1.f / 64.f) - mean * mean;
        float rstd = rsqrtf(var + EPSLN);
        float qn[4];
#pragma unroll
        for (int ni = 0; ni < 4; ++ni)
            qn[ni] = (acc[ni][reg] - mean) * rstd * gqv[ni] + bqv[ni];

        s1 = 0.f; s2 = 0.f;
#pragma unroll
        for (int ni = 0; ni < 4; ++ni) {
            float v = acc[4 + ni][reg];
            s1 += v; s2 += v * v;
        }
#pragma unroll
        for (int off = 1; off < 16; off <<= 1) {
            s1 += __shfl_xor(s1, off);
            s2 += __shfl_xor(s2, off);
        }
        mean = s1 * (1.f / 64.f);
        var  = s2 * (1.f / 64.f) - mean * mean;
        rstd = rsqrtf(var + EPSLN);
        float kn[4];
#pragma unroll
        for (int ni = 0; ni < 4; ++ni)
            kn[ni] = (acc[4 + ni][reg] - mean) * rstd * gkv[ni] + bkv[ni];

        float da = 0.f, d0 = 0.f, d1 = 0.f;
#pragma unroll
        for (int ni = 0; ni < 4; ++ni) {
            da += qn[ni] * wav[ni];
            d0 += qn[ni] * ws0[ni];
            d1 += qn[ni] * ws1[ni];
        }
#pragma unroll
        for (int off = 1; off < 16; off <<= 1) {
            da += __shfl_xor(da, off);
            d0 += __shfl_xor(d0, off);
            d1 += __shfl_xor(d1, off);
        }

        if (tokr < NROW) {
            size_t base = (size_t)tokr * 64;
            int bidx = tokr / TDIM;
            int ti   = tokr - bidx * TDIM;
#pragma unroll
            for (int ni = 0; ni < 4; ++ni) {
                int c = lr + 16 * ni;
                qb[base + c] = f2bf(qn[ni]);
                kb[base + c] = f2bf(kn[ni]);
                vb[base + c] = f2bf(acc[8 + ni][reg]);
            }
            if (lr == 0 && ti >= 1) {
                int p = bidx * TPATCH + ti - 1;
                float av = da + ba0;
                float sp = (av > 20.f) ? av : log1pf(__expf(av));
                a8[p] = sp * (1.f / SCALE);
                float sx = 1.f / (1.f + __expf(-(d0 + bs0)));
                float sy = 1.f / (1.f + __expf(-(d1 + bs1)));
                isx[p] = 0.5f / (sx * sx);
                isy[p] = 0.5f / (sy * sy);
            }
        }
    }
}

// ---------------------------------------------------------------------------
// Kernel 1b: vb [token][dh] -> vT [b][dh][token] via LDS transpose.
// ---------------------------------------------------------------------------
__global__ __launch_bounds__(256) void vtrans_kernel(
    const unsigned short* __restrict__ vb, unsigned short* __restrict__ vT)
{
    __shared__ unsigned short tile[64][LDP];   // [dh][token]
    const int t  = threadIdx.x;
    const int bb = blockIdx.y;
    const int t0 = blockIdx.x * 64;

#pragma unroll
    for (int it = 0; it < 2; ++it) {
        int lin = t + it * 256;
        int tok = lin >> 3;
        int d0  = (lin & 7) * 8;
        short8v v8 = {0, 0, 0, 0, 0, 0, 0, 0};
        if (t0 + tok < TDIM)
            v8 = *(const short8v*)&vb[((size_t)bb * TDIM + t0 + tok) * 64 + d0];
        union { short8v v; unsigned short s[8]; } u; u.v = v8;
#pragma unroll
        for (int j = 0; j < 8; ++j) tile[d0 + j][tok] = u.s[j];
    }
    __syncthreads();

    const int dh = t >> 2;
    const int ch = t & 3;
    short8v o0 = *(const short8v*)&tile[dh][ch * 16];
    short8v o1 = *(const short8v*)&tile[dh][ch * 16 + 8];
    size_t dst = ((size_t)bb * 64 + dh) * VTLD + t0 + ch * 16;
    *(short8v*)&vT[dst]     = o0;
    *(short8v*)&vT[dst + 8] = o1;
}

// ---------------------------------------------------------------------------
// Kernel 2: MFMA flash attention (measured-good: raw barriers, dbuf K/V,
// issue-early/write-late, DPP softmax, Q direct from global). Unchanged.
// ---------------------------------------------------------------------------
__global__ __launch_bounds__(256) void attn_mfma_kernel(
    const unsigned short* __restrict__ qb, const unsigned short* __restrict__ kb,
    const unsigned short* __restrict__ vT,
    const float* __restrict__ a8, const float* __restrict__ isx,
    const float* __restrict__ isy, float* __restrict__ out)
{
    __shared__ unsigned short Ks[2][64][LDP];
    __shared__ unsigned short Vt[2][64][LDP];   // [dh][key]
    __shared__ unsigned short Pt[4][16][LDP];   // per-wave [q][key]

    const int t  = threadIdx.x;
    const int wv = t >> 6;
    const int ln = t & 63;
    const int lq = ln >> 4;
    const int lr = ln & 15;
    const int bb = blockIdx.y;
    const int q0 = blockIdx.x * 64;

    const int qrow = min(q0 + wv * 16 + lr, TDIM - 1);
    const size_t qbase = ((size_t)bb * TDIM + qrow) * 64;
    const short8v aq0 = *(const short8v*)&qb[qbase + lq * 8];
    const short8v aq1 = *(const short8v*)&qb[qbase + 32 + lq * 8];

    float a8q[4], sxq[4], syq[4], qpy[4], qpx[4];
    bool  hasS[4];
#pragma unroll
    for (int reg = 0; reg < 4; ++reg) {
        int qg = q0 + wv * 16 + lq * 4 + reg;
        hasS[reg] = false;
        a8q[reg] = 0.f; sxq[reg] = 0.f; syq[reg] = 0.f; qpy[reg] = 0.f; qpx[reg] = 0.f;
        if (qg >= 1 && qg < TDIM) {
            int qp = qg - 1;
            hasS[reg] = true;
            a8q[reg] = a8 [bb * TPATCH + qp];
            sxq[reg] = isx[bb * TPATCH + qp];
            syq[reg] = isy[bb * TPATCH + qp];
            qpy[reg] = (float)(qp >> 5);
            qpx[reg] = (float)(qp & 31);
        }
    }

    float m[4]  = {-1e30f, -1e30f, -1e30f, -1e30f};
    float l[4]  = {0.f, 0.f, 0.f, 0.f};
    f32x4 oacc[4];
#pragma unroll
    for (int ni = 0; ni < 4; ++ni) oacc[ni] = (f32x4){0.f, 0.f, 0.f, 0.f};

    const int sk_row = t >> 3;
    const int sk_d0  = (t & 7) * 8;
    short8v rk[2], rv[2];

#define ALOAD(KT0)                                                             \
    do {                                                                       \
        _Pragma("unroll") for (int it = 0; it < 2; ++it) {                     \
            int key = sk_row + 32 * it;                                        \
            int kg  = (KT0) + key;                                             \
            rk[it] = (kg < TDIM)                                               \
                ? *(const short8v*)&kb[((size_t)bb * TDIM + kg) * 64 + sk_d0]  \
                : (short8v){0, 0, 0, 0, 0, 0, 0, 0};                           \
            rv[it] = *(const short8v*)&vT[((size_t)bb * 64 + key) * VTLD +     \
                                          (KT0) + sk_d0];                      \
        }                                                                      \
    } while (0)

#define ASTORE(BUF)                                                            \
    do {                                                                       \
        _Pragma("unroll") for (int it = 0; it < 2; ++it) {                     \
            *(short8v*)&Ks[BUF][sk_row + 32 * it][sk_d0] = rk[it];             \
            *(short8v*)&Vt[BUF][sk_row + 32 * it][sk_d0] = rv[it];             \
        }                                                                      \
    } while (0)

    ALOAD(0);
    ASTORE(0);
    wg_barrier();

    for (int tile = 0; tile < NTILES; ++tile) {
        const int kt0 = tile * 64;
        const int buf = tile & 1;
        if (tile + 1 < NTILES) ALOAD(kt0 + 64);

        f32x4 sac[4];
#pragma unroll
        for (int ni = 0; ni < 4; ++ni) sac[ni] = (f32x4){0.f, 0.f, 0.f, 0.f};
#pragma unroll
        for (int ni = 0; ni < 4; ++ni) {
            short8v b0 = *(const short8v*)&Ks[buf][16 * ni + lr][lq * 8];
            short8v b1 = *(const short8v*)&Ks[buf][16 * ni + lr][32 + lq * 8];
            sac[ni] = __builtin_amdgcn_mfma_f32_16x16x32_bf16(aq0, b0, sac[ni], 0, 0, 0);
            sac[ni] = __builtin_amdgcn_mfma_f32_16x16x32_bf16(aq1, b1, sac[ni], 0, 0, 0);
        }

#pragma unroll
        for (int ni = 0; ni < 4; ++ni) {
            int key = kt0 + 16 * ni + lr;
            int kp  = key - 1;
            float ky = (float)(kp >> 5);
            float kx = (float)(kp & 31);
            bool kvalid = (key >= 1) && (key < TDIM);
#pragma unroll
            for (int reg = 0; reg < 4; ++reg) {
                float z = sac[ni][reg] * (1.f / SCALE);
                if (kvalid && hasS[reg]) {
                    float dy = qpy[reg] - ky;
                    float dx = qpx[reg] - kx;
                    z += a8q[reg] * __expf(-(dx * dx * sxq[reg] + dy * dy * syq[reg]));
                }
                if (key >= TDIM) z = -1e30f;
                sac[ni][reg] = z;
            }
        }

        float scf[4];
#pragma unroll
        for (int reg = 0; reg < 4; ++reg) {
            float mx = fmaxf(fmaxf(sac[0][reg], sac[1][reg]),
                             fmaxf(sac[2][reg], sac[3][reg]));
            mx = red16_max(mx);
            float mn = fmaxf(m[reg], mx);
            scf[reg] = __expf(m[reg] - mn);
            m[reg] = mn;
            float ts = 0.f;
#pragma unroll
            for (int ni = 0; ni < 4; ++ni) {
                float pp = __expf(sac[ni][reg] - mn);
                sac[ni][reg] = pp;
                ts += pp;
            }
            ts = red16_sum(ts);
            l[reg] = l[reg] * scf[reg] + ts;
        }
#pragma unroll
        for (int ni = 0; ni < 4; ++ni)
#pragma unroll
            for (int reg = 0; reg < 4; ++reg)
                oacc[ni][reg] *= scf[reg];

#pragma unroll
        for (int ni = 0; ni < 4; ++ni)
#pragma unroll
            for (int reg = 0; reg < 4; ++reg)
                Pt[wv][lq * 4 + reg][16 * ni + lr] = f2bf(sac[ni][reg]);

#pragma unroll
        for (int ks = 0; ks < 2; ++ks) {
            short8v pa = *(const short8v*)&Pt[wv][lr][ks * 32 + lq * 8];
#pragma unroll
            for (int ni = 0; ni < 4; ++ni) {
                short8v bv = *(const short8v*)&Vt[buf][16 * ni + lr][ks * 32 + lq * 8];
                oacc[ni] = __builtin_amdgcn_mfma_f32_16x16x32_bf16(pa, bv, oacc[ni], 0, 0, 0);
            }
        }

        if (tile + 1 < NTILES) ASTORE(buf ^ 1);
        wg_barrier();
    }
#undef ALOAD
#undef ASTORE

#pragma unroll
    for (int reg = 0; reg < 4; ++reg) {
        int qg = q0 + wv * 16 + lq * 4 + reg;
        if (qg < TDIM) {
            float rl = 1.f / l[reg];
#pragma unroll
            for (int ni = 0; ni < 4; ++ni)
                out[((size_t)bb * TDIM + qg) * 64 + 16 * ni + lr] = oacc[ni][reg] * rl;
        }
    }
}

extern "C" void kernel_launch(void* const* d_in, const int* in_sizes, int n_in,
                              void* d_out, int out_size, void* d_ws, size_t ws_size,
                              hipStream_t stream)
{
    const float* x    = (const float*)d_in[0];
    const float* Wq   = (const float*)d_in[1];
    const float* Wk   = (const float*)d_in[2];
    const float* Wv   = (const float*)d_in[3];
    const float* gq   = (const float*)d_in[4];
    const float* bq   = (const float*)d_in[5];
    const float* gk   = (const float*)d_in[6];
    const float* bk   = (const float*)d_in[7];
    const float* Wsig = (const float*)d_in[8];
    const float* bsig = (const float*)d_in[9];
    const float* Wa   = (const float*)d_in[10];
    const float* ba   = (const float*)d_in[11];
    float* out = (float*)d_out;

    // ---- workspace layout ----
    char* w = (char*)d_ws;
    const size_t NQ = (size_t)NROW * 64;
    unsigned short* qb = (unsigned short*)w;   w += NQ * 2;
    unsigned short* kb = (unsigned short*)w;   w += NQ * 2;
    unsigned short* vb = (unsigned short*)w;   w += NQ * 2;
    unsigned short* vT = (unsigned short*)w;   w += (size_t)BDIM * 64 * VTLD * 2;
    float* a8  = (float*)w;                    w += (size_t)BDIM * TPATCH * 4;
    float* isx = (float*)w;                    w += (size_t)BDIM * TPATCH * 4;
    float* isy = (float*)w;                    w += (size_t)BDIM * TPATCH * 4;
    unsigned short* wTt = (unsigned short*)w;  w += (size_t)192 * DDIM * 2;

    hipLaunchKernelGGL(prep_w_kernel, dim3(192), dim3(256), 0, stream,
                       Wq, Wk, Wv, wTt);

    const int nblk1 = NROW / 32;   // 1025 blocks of 32 rows (exact cover)
    hipLaunchKernelGGL(qkv_tile_kernel, dim3(nblk1), dim3(128), 0, stream,
                       x, wTt, gq, bq, gk, bk, Wsig, bsig, Wa, ba,
                       qb, kb, vb, a8, isx, isy);

    hipLaunchKernelGGL(vtrans_kernel, dim3(17, BDIM), dim3(256), 0, stream,
                       vb, vT);

    hipLaunchKernelGGL(attn_mfma_kernel, dim3(17, BDIM), dim3(256), 0, stream,
                       qb, kb, vT, a8, isx, isy, out);
}

// Round 16
// 106.333 us; speedup vs baseline: 1.1667x; 1.0401x over previous
//
#include <hip/hip_runtime.h>
#include <hip/hip_bf16.h>
#include <math.h>

#define BDIM 32
#define TDIM 1025
#define DDIM 768
#define GRIDW 32
#define TPATCH 1024
#define SCALE 8.0f
#define EPSLN 1e-5f
#define NROW (BDIM * TDIM)   // 32800
#define VTLD 1088            // vT row stride (elements, 16B-aligned)
#define LDP  72              // LDS row stride for attn tiles
#define LDQ  40              // LDS row stride for qkv tiles (BK=32)
#define NTILES 17
#define NQT   9              // ceil(1025/128) q-tiles

typedef __attribute__((ext_vector_type(8))) short short8v;   // 8 bf16 (4 VGPRs)
typedef __attribute__((ext_vector_type(4))) float f32x4;     // MFMA C/D frag

__device__ __forceinline__ unsigned short f2bf(float f) {
    unsigned int u = __float_as_uint(f);
    u += 0x7FFFu + ((u >> 16) & 1u);      // round-to-nearest-even
    return (unsigned short)(u >> 16);
}

__device__ __forceinline__ short8v pack8(float4 a, float4 b) {
    union { short8v v; unsigned short s[8]; } u;
    u.s[0] = f2bf(a.x); u.s[1] = f2bf(a.y); u.s[2] = f2bf(a.z); u.s[3] = f2bf(a.w);
    u.s[4] = f2bf(b.x); u.s[5] = f2bf(b.y); u.s[6] = f2bf(b.z); u.s[7] = f2bf(b.w);
    return u.v;
}

// Raw workgroup barrier (no vmcnt(0) drain) — attn only.
__device__ __forceinline__ void wg_barrier() {
    asm volatile("s_waitcnt lgkmcnt(0)" ::: "memory");
    __builtin_amdgcn_s_barrier();
    __builtin_amdgcn_sched_barrier(0);
}

// ---- 16-lane DPP reductions (attn only) ----
template<int CTRL>
__device__ __forceinline__ float dpp_f(float x) {
    return __int_as_float(__builtin_amdgcn_update_dpp(
        __float_as_int(x), __float_as_int(x), CTRL, 0xF, 0xF, true));
}
__device__ __forceinline__ float red16_max(float x) {
    x = fmaxf(x, dpp_f<0xB1>(x));
    x = fmaxf(x, dpp_f<0x4E>(x));
    x = fmaxf(x, dpp_f<0x124>(x));
    x = fmaxf(x, dpp_f<0x128>(x));
    return x;
}
__device__ __forceinline__ float red16_sum(float x) {
    x += dpp_f<0xB1>(x);
    x += dpp_f<0x4E>(x);
    x += dpp_f<0x124>(x);
    x += dpp_f<0x128>(x);
    return x;
}

// ---------------------------------------------------------------------------
// Kernel 0: W -> bf16, transposed: wT[c][k], c = 0..191 (q|k|v), k = 0..767
// ---------------------------------------------------------------------------
__global__ __launch_bounds__(256) void prep_w_kernel(
    const float* __restrict__ Wq, const float* __restrict__ Wk,
    const float* __restrict__ Wv, unsigned short* __restrict__ wT)
{
    const int c = blockIdx.x;
    const float* W = (c < 64) ? Wq : (c < 128) ? Wk : Wv;
    const int cc = c & 63;
    for (int k = threadIdx.x; k < DDIM; k += 256)
        wT[(size_t)c * DDIM + k] = f2bf(W[(size_t)k * 64 + cc]);
}

// ---------------------------------------------------------------------------
// Kernel 1: MFMA QKV projection + fused LN + heads — R12-measured-best (63us),
// FROZEN verbatim. 513 blocks x 4 waves; 64 rows x 192 cols; BK=32, 24 steps;
// dbuf LDS; STORE -> LOAD(k+1) -> __syncthreads -> COMPUTE; shfl_xor epilogue.
// ---------------------------------------------------------------------------
__global__ __launch_bounds__(256) void qkv_tile_kernel(
    const float* __restrict__ x, const unsigned short* __restrict__ wT,
    const float* __restrict__ gq, const float* __restrict__ bq,
    const float* __restrict__ gk, const float* __restrict__ bk,
    const float* __restrict__ Wsig, const float* __restrict__ bsig,
    const float* __restrict__ Wa, const float* __restrict__ ba,
    unsigned short* __restrict__ qb, unsigned short* __restrict__ kb,
    unsigned short* __restrict__ vb,
    float* __restrict__ a8, float* __restrict__ isx, float* __restrict__ isy)
{
    __shared__ unsigned short As[2][64][LDQ];    // 10.2 KB
    __shared__ unsigned short Bs[2][192][LDQ];   // 30.7 KB

    const int t  = threadIdx.x;
    const int wv = t >> 6;
    const int ln = t & 63;
    const int lq = ln >> 4;
    const int lr = ln & 15;
    const int tok0 = blockIdx.x * 64;           // flat row (b*TDIM + ti)

    const int arow = t >> 2;
    const int aseg = t & 3;
    const float* aptr = x + (size_t)min(tok0 + arow, NROW - 1) * DDIM + aseg * 8;
    const int brow = t >> 2;
    const int bseg = t & 3;

    f32x4 acc[12];
#pragma unroll
    for (int ni = 0; ni < 12; ++ni) acc[ni] = (f32x4){0.f, 0.f, 0.f, 0.f};

    float4 ra0, ra1;
    short8v rb0, rb1, rb2;

    ra0 = *(const float4*)(aptr + 0);
    ra1 = *(const float4*)(aptr + 4);
    rb0 = *(const short8v*)&wT[(size_t)(brow +   0) * DDIM + bseg * 8];
    rb1 = *(const short8v*)&wT[(size_t)(brow +  64) * DDIM + bseg * 8];
    rb2 = *(const short8v*)&wT[(size_t)(brow + 128) * DDIM + bseg * 8];

#pragma unroll
    for (int ks = 0; ks < 24; ++ks) {
        const int buf = ks & 1;
        *(short8v*)&As[buf][arow][aseg * 8]        = pack8(ra0, ra1);
        *(short8v*)&Bs[buf][brow +   0][bseg * 8]  = rb0;
        *(short8v*)&Bs[buf][brow +  64][bseg * 8]  = rb1;
        *(short8v*)&Bs[buf][brow + 128][bseg * 8]  = rb2;
        if (ks + 1 < 24) {
            const int k0 = (ks + 1) * 32;
            ra0 = *(const float4*)(aptr + k0 + 0);
            ra1 = *(const float4*)(aptr + k0 + 4);
            rb0 = *(const short8v*)&wT[(size_t)(brow +   0) * DDIM + k0 + bseg * 8];
            rb1 = *(const short8v*)&wT[(size_t)(brow +  64) * DDIM + k0 + bseg * 8];
            rb2 = *(const short8v*)&wT[(size_t)(brow + 128) * DDIM + k0 + bseg * 8];
        }
        __syncthreads();
        short8v af = *(const short8v*)&As[buf][wv * 16 + lr][lq * 8];
#pragma unroll
        for (int ni = 0; ni < 12; ++ni) {
            short8v bf = *(const short8v*)&Bs[buf][16 * ni + lr][lq * 8];
            acc[ni] = __builtin_amdgcn_mfma_f32_16x16x32_bf16(af, bf, acc[ni], 0, 0, 0);
        }
    }

    float gqv[4], bqv[4], gkv[4], bkv[4], wav[4], ws0[4], ws1[4];
#pragma unroll
    for (int ni = 0; ni < 4; ++ni) {
        int c = lr + 16 * ni;
        gqv[ni] = gq[c]; bqv[ni] = bq[c];
        gkv[ni] = gk[c]; bkv[ni] = bk[c];
        wav[ni] = Wa[c];
        ws0[ni] = Wsig[2 * c];
        ws1[ni] = Wsig[2 * c + 1];
    }
    const float ba0 = ba[0], bs0 = bsig[0], bs1 = bsig[1];

#pragma unroll
    for (int reg = 0; reg < 4; ++reg) {
        const int tokr = tok0 + wv * 16 + lq * 4 + reg;

        float s1 = 0.f, s2 = 0.f;
#pragma unroll
        for (int ni = 0; ni < 4; ++ni) {
            float v = acc[ni][reg];
            s1 += v; s2 += v * v;
        }
#pragma unroll
        for (int off = 1; off < 16; off <<= 1) {
            s1 += __shfl_xor(s1, off);
            s2 += __shfl_xor(s2, off);
        }
        float mean = s1 * (1.f / 64.f);
        float var  = s2 * (1.f / 64.f) - mean * mean;
        float rstd = rsqrtf(var + EPSLN);
        float qn[4];
#pragma unroll
        for (int ni = 0; ni < 4; ++ni)
            qn[ni] = (acc[ni][reg] - mean) * rstd * gqv[ni] + bqv[ni];

        s1 = 0.f; s2 = 0.f;
#pragma unroll
        for (int ni = 0; ni < 4; ++ni) {
            float v = acc[4 + ni][reg];
            s1 += v; s2 += v * v;
        }
#pragma unroll
        for (int off = 1; off < 16; off <<= 1) {
            s1 += __shfl_xor(s1, off);
            s2 += __shfl_xor(s2, off);
        }
        mean = s1 * (1.f / 64.f);
        var  = s2 * (1.f / 64.f) - mean * mean;
        rstd = rsqrtf(var + EPSLN);
        float kn[4];
#pragma unroll
        for (int ni = 0; ni < 4; ++ni)
            kn[ni] = (acc[4 + ni][reg] - mean) * rstd * gkv[ni] + bkv[ni];

        float da = 0.f, d0 = 0.f, d1 = 0.f;
#pragma unroll
        for (int ni = 0; ni < 4; ++ni) {
            da += qn[ni] * wav[ni];
            d0 += qn[ni] * ws0[ni];
            d1 += qn[ni] * ws1[ni];
        }
#pragma unroll
        for (int off = 1; off < 16; off <<= 1) {
            da += __shfl_xor(da, off);
            d0 += __shfl_xor(d0, off);
            d1 += __shfl_xor(d1, off);
        }

        if (tokr < NROW) {
            size_t base = (size_t)tokr * 64;
            int bidx = tokr / TDIM;
            int ti   = tokr - bidx * TDIM;
#pragma unroll
            for (int ni = 0; ni < 4; ++ni) {
                int c = lr + 16 * ni;
                qb[base + c] = f2bf(qn[ni]);
                kb[base + c] = f2bf(kn[ni]);
                vb[base + c] = f2bf(acc[8 + ni][reg]);
            }
            if (lr == 0 && ti >= 1) {
                int p = bidx * TPATCH + ti - 1;
                float av = da + ba0;
                float sp = (av > 20.f) ? av : log1pf(__expf(av));
                a8[p] = sp * (1.f / SCALE);
                float sx = 1.f / (1.f + __expf(-(d0 + bs0)));
                float sy = 1.f / (1.f + __expf(-(d1 + bs1)));
                isx[p] = 0.5f / (sx * sx);
                isy[p] = 0.5f / (sy * sy);
            }
        }
    }
}

// ---------------------------------------------------------------------------
// Kernel 1b: vb -> vT via LDS transpose. Grid (batch, token-tile) so all of a
// batch's blocks land on XCD batch%8 (vT then read by attn on the same XCD).
// ---------------------------------------------------------------------------
__global__ __launch_bounds__(256) void vtrans_kernel(
    const unsigned short* __restrict__ vb, unsigned short* __restrict__ vT)
{
    __shared__ unsigned short tile[64][LDP];   // [dh][token]
    const int t  = threadIdx.x;
    const int bb = blockIdx.x;                 // batch (XCD key)
    const int t0 = blockIdx.y * 64;

#pragma unroll
    for (int it = 0; it < 2; ++it) {
        int lin = t + it * 256;
        int tok = lin >> 3;
        int d0  = (lin & 7) * 8;
        short8v v8 = {0, 0, 0, 0, 0, 0, 0, 0};
        if (t0 + tok < TDIM)
            v8 = *(const short8v*)&vb[((size_t)bb * TDIM + t0 + tok) * 64 + d0];
        union { short8v v; unsigned short s[8]; } u; u.v = v8;
#pragma unroll
        for (int j = 0; j < 8; ++j) tile[d0 + j][tok] = u.s[j];
    }
    __syncthreads();

    const int dh = t >> 2;
    const int ch = t & 3;
    short8v o0 = *(const short8v*)&tile[dh][ch * 16];
    short8v o1 = *(const short8v*)&tile[dh][ch * 16 + 8];
    size_t dst = ((size_t)bb * 64 + dh) * VTLD + t0 + ch * 16;
    *(short8v*)&vT[dst]     = o0;
    *(short8v*)&vT[dst + 8] = o1;
}

// ---------------------------------------------------------------------------
// Kernel 2: MFMA flash attention, QBLK=128 (2 q-frags per wave): 2x MFMA per
// staged K/V tile, half the blocks/barriers. Grid (batch, qtile) -> all of a
// batch's 9 q-tiles on one XCD (K/V L2-resident). setprio around MFMA (T5).
// ---------------------------------------------------------------------------
__global__ __launch_bounds__(256) void attn_mfma_kernel(
    const unsigned short* __restrict__ qb, const unsigned short* __restrict__ kb,
    const unsigned short* __restrict__ vT,
    const float* __restrict__ a8, const float* __restrict__ isx,
    const float* __restrict__ isy, float* __restrict__ out)
{
    __shared__ unsigned short Ks[2][64][LDP];
    __shared__ unsigned short Vt[2][64][LDP];   // [dh][key]
    __shared__ unsigned short Pt[4][32][LDP];   // per-wave [q(32)][key]

    const int t  = threadIdx.x;
    const int wv = t >> 6;
    const int ln = t & 63;
    const int lq = ln >> 4;
    const int lr = ln & 15;
    const int bb = blockIdx.x;                  // batch (XCD key)
    const int q0 = blockIdx.y * 128;

    // ---- Q fragments, 2 per wave (rows clamped; results masked) ----
    short8v aq[2][2];
#pragma unroll
    for (int mi = 0; mi < 2; ++mi) {
        int qrow = min(q0 + wv * 32 + mi * 16 + lr, TDIM - 1);
        size_t qbase = ((size_t)bb * TDIM + qrow) * 64;
        aq[mi][0] = *(const short8v*)&qb[qbase + lq * 8];
        aq[mi][1] = *(const short8v*)&qb[qbase + 32 + lq * 8];
    }

    // ---- per-(mi,reg) query metadata ----
    float a8q[2][4], sxq[2][4], syq[2][4], qpy[2][4], qpx[2][4];
    bool  hasS[2][4];
#pragma unroll
    for (int mi = 0; mi < 2; ++mi)
#pragma unroll
    for (int reg = 0; reg < 4; ++reg) {
        int qg = q0 + wv * 32 + mi * 16 + lq * 4 + reg;
        hasS[mi][reg] = false;
        a8q[mi][reg] = 0.f; sxq[mi][reg] = 0.f; syq[mi][reg] = 0.f;
        qpy[mi][reg] = 0.f; qpx[mi][reg] = 0.f;
        if (qg >= 1 && qg < TDIM) {
            int qp = qg - 1;
            hasS[mi][reg] = true;
            a8q[mi][reg] = a8 [bb * TPATCH + qp];
            sxq[mi][reg] = isx[bb * TPATCH + qp];
            syq[mi][reg] = isy[bb * TPATCH + qp];
            qpy[mi][reg] = (float)(qp >> 5);
            qpx[mi][reg] = (float)(qp & 31);
        }
    }

    float m[2][4], l[2][4];
    f32x4 oacc[2][4];
#pragma unroll
    for (int mi = 0; mi < 2; ++mi)
#pragma unroll
    for (int ni = 0; ni < 4; ++ni) {
        oacc[mi][ni] = (f32x4){0.f, 0.f, 0.f, 0.f};
        m[mi][ni] = -1e30f;   // reuse [ni] slot as [reg] for m/l below
        l[mi][ni] = 0.f;
    }

    const int sk_row = t >> 3;
    const int sk_d0  = (t & 7) * 8;
    short8v rk[2], rv[2];

#define ALOAD(KT0)                                                             \
    do {                                                                       \
        _Pragma("unroll") for (int it = 0; it < 2; ++it) {                     \
            int key = sk_row + 32 * it;                                        \
            int kg  = (KT0) + key;                                             \
            rk[it] = (kg < TDIM)                                               \
                ? *(const short8v*)&kb[((size_t)bb * TDIM + kg) * 64 + sk_d0]  \
                : (short8v){0, 0, 0, 0, 0, 0, 0, 0};                           \
            rv[it] = *(const short8v*)&vT[((size_t)bb * 64 + key) * VTLD +     \
                                          (KT0) + sk_d0];                      \
        }                                                                      \
    } while (0)

#define ASTORE(BUF)                                                            \
    do {                                                                       \
        _Pragma("unroll") for (int it = 0; it < 2; ++it) {                     \
            *(short8v*)&Ks[BUF][sk_row + 32 * it][sk_d0] = rk[it];             \
            *(short8v*)&Vt[BUF][sk_row + 32 * it][sk_d0] = rv[it];             \
        }                                                                      \
    } while (0)

    ALOAD(0);
    ASTORE(0);
    wg_barrier();

    for (int tile = 0; tile < NTILES; ++tile) {
        const int kt0 = tile * 64;
        const int buf = tile & 1;
        if (tile + 1 < NTILES) ALOAD(kt0 + 64);

        // ---- scores: S = Q K^T (2 q-frags x 4 key-frags) ----
        f32x4 sac[2][4];
#pragma unroll
        for (int mi = 0; mi < 2; ++mi)
#pragma unroll
        for (int ni = 0; ni < 4; ++ni) sac[mi][ni] = (f32x4){0.f, 0.f, 0.f, 0.f};
        __builtin_amdgcn_s_setprio(1);
#pragma unroll
        for (int ni = 0; ni < 4; ++ni) {
            short8v b0 = *(const short8v*)&Ks[buf][16 * ni + lr][lq * 8];
            short8v b1 = *(const short8v*)&Ks[buf][16 * ni + lr][32 + lq * 8];
#pragma unroll
            for (int mi = 0; mi < 2; ++mi) {
                sac[mi][ni] = __builtin_amdgcn_mfma_f32_16x16x32_bf16(aq[mi][0], b0, sac[mi][ni], 0, 0, 0);
                sac[mi][ni] = __builtin_amdgcn_mfma_f32_16x16x32_bf16(aq[mi][1], b1, sac[mi][ni], 0, 0, 0);
            }
        }
        __builtin_amdgcn_s_setprio(0);

        // ---- bias + mask ----
#pragma unroll
        for (int ni = 0; ni < 4; ++ni) {
            int key = kt0 + 16 * ni + lr;
            int kp  = key - 1;
            float ky = (float)(kp >> 5);
            float kx = (float)(kp & 31);
            bool kvalid = (key >= 1) && (key < TDIM);
#pragma unroll
            for (int mi = 0; mi < 2; ++mi)
#pragma unroll
            for (int reg = 0; reg < 4; ++reg) {
                float z = sac[mi][ni][reg] * (1.f / SCALE);
                if (kvalid && hasS[mi][reg]) {
                    float dy = qpy[mi][reg] - ky;
                    float dx = qpx[mi][reg] - kx;
                    z += a8q[mi][reg] * __expf(-(dx * dx * sxq[mi][reg] + dy * dy * syq[mi][reg]));
                }
                if (key >= TDIM) z = -1e30f;
                sac[mi][ni][reg] = z;
            }
        }

        // ---- online softmax (DPP reductions) ----
        float scf[2][4];
#pragma unroll
        for (int mi = 0; mi < 2; ++mi)
#pragma unroll
        for (int reg = 0; reg < 4; ++reg) {
            float mx = fmaxf(fmaxf(sac[mi][0][reg], sac[mi][1][reg]),
                             fmaxf(sac[mi][2][reg], sac[mi][3][reg]));
            mx = red16_max(mx);
            float mn = fmaxf(m[mi][reg], mx);
            scf[mi][reg] = __expf(m[mi][reg] - mn);
            m[mi][reg] = mn;
            float ts = 0.f;
#pragma unroll
            for (int ni = 0; ni < 4; ++ni) {
                float pp = __expf(sac[mi][ni][reg] - mn);
                sac[mi][ni][reg] = pp;
                ts += pp;
            }
            ts = red16_sum(ts);
            l[mi][reg] = l[mi][reg] * scf[mi][reg] + ts;
        }
#pragma unroll
        for (int mi = 0; mi < 2; ++mi)
#pragma unroll
        for (int ni = 0; ni < 4; ++ni)
#pragma unroll
            for (int reg = 0; reg < 4; ++reg)
                oacc[mi][ni][reg] *= scf[mi][reg];

        // ---- publish P (wave-private tile, same-wave LDS ordering) ----
#pragma unroll
        for (int mi = 0; mi < 2; ++mi)
#pragma unroll
        for (int ni = 0; ni < 4; ++ni)
#pragma unroll
            for (int reg = 0; reg < 4; ++reg)
                Pt[wv][mi * 16 + lq * 4 + reg][16 * ni + lr] = f2bf(sac[mi][ni][reg]);

        // ---- PV: O += P V ----
        __builtin_amdgcn_s_setprio(1);
#pragma unroll
        for (int ks = 0; ks < 2; ++ks) {
#pragma unroll
            for (int mi = 0; mi < 2; ++mi) {
                short8v pa = *(const short8v*)&Pt[wv][mi * 16 + lr][ks * 32 + lq * 8];
#pragma unroll
                for (int ni = 0; ni < 4; ++ni) {
                    short8v bv = *(const short8v*)&Vt[buf][16 * ni + lr][ks * 32 + lq * 8];
                    oacc[mi][ni] = __builtin_amdgcn_mfma_f32_16x16x32_bf16(pa, bv, oacc[mi][ni], 0, 0, 0);
                }
            }
        }
        __builtin_amdgcn_s_setprio(0);

        if (tile + 1 < NTILES) ASTORE(buf ^ 1);
        wg_barrier();
    }
#undef ALOAD
#undef ASTORE

    // ---- epilogue ----
#pragma unroll
    for (int mi = 0; mi < 2; ++mi)
#pragma unroll
    for (int reg = 0; reg < 4; ++reg) {
        int qg = q0 + wv * 32 + mi * 16 + lq * 4 + reg;
        if (qg < TDIM) {
            float rl = 1.f / l[mi][reg];
#pragma unroll
            for (int ni = 0; ni < 4; ++ni)
                out[((size_t)bb * TDIM + qg) * 64 + 16 * ni + lr] = oacc[mi][ni][reg] * rl;
        }
    }
}

extern "C" void kernel_launch(void* const* d_in, const int* in_sizes, int n_in,
                              void* d_out, int out_size, void* d_ws, size_t ws_size,
                              hipStream_t stream)
{
    const float* x    = (const float*)d_in[0];
    const float* Wq   = (const float*)d_in[1];
    const float* Wk   = (const float*)d_in[2];
    const float* Wv   = (const float*)d_in[3];
    const float* gq   = (const float*)d_in[4];
    const float* bq   = (const float*)d_in[5];
    const float* gk   = (const float*)d_in[6];
    const float* bk   = (const float*)d_in[7];
    const float* Wsig = (const float*)d_in[8];
    const float* bsig = (const float*)d_in[9];
    const float* Wa   = (const float*)d_in[10];
    const float* ba   = (const float*)d_in[11];
    float* out = (float*)d_out;

    // ---- workspace layout ----
    char* w = (char*)d_ws;
    const size_t NQ = (size_t)NROW * 64;
    unsigned short* qb = (unsigned short*)w;   w += NQ * 2;
    unsigned short* kb = (unsigned short*)w;   w += NQ * 2;
    unsigned short* vb = (unsigned short*)w;   w += NQ * 2;
    unsigned short* vT = (unsigned short*)w;   w += (size_t)BDIM * 64 * VTLD * 2;
    float* a8  = (float*)w;                    w += (size_t)BDIM * TPATCH * 4;
    float* isx = (float*)w;                    w += (size_t)BDIM * TPATCH * 4;
    float* isy = (float*)w;                    w += (size_t)BDIM * TPATCH * 4;
    unsigned short* wT = (unsigned short*)w;   w += (size_t)192 * DDIM * 2;

    hipLaunchKernelGGL(prep_w_kernel, dim3(192), dim3(256), 0, stream,
                       Wq, Wk, Wv, wT);

    const int nblk1 = (NROW + 63) / 64;   // 513
    hipLaunchKernelGGL(qkv_tile_kernel, dim3(nblk1), dim3(256), 0, stream,
                       x, wT, gq, bq, gk, bk, Wsig, bsig, Wa, ba,
                       qb, kb, vb, a8, isx, isy);

    hipLaunchKernelGGL(vtrans_kernel, dim3(BDIM, 17), dim3(256), 0, stream,
                       vb, vT);

    hipLaunchKernelGGL(attn_mfma_kernel, dim3(BDIM, NQT), dim3(256), 0, stream,
                       qb, kb, vT, a8, isx, isy, out);
}

// Round 17
// 104.656 us; speedup vs baseline: 1.1854x; 1.0160x over previous
//
#include <hip/hip_runtime.h>
#include <hip/hip_bf16.h>
#include <math.h>

#define BDIM 32
#define TDIM 1025
#define DDIM 768
#define GRIDW 32
#define TPATCH 1024
#define SCALE 8.0f
#define EPSLN 1e-5f
#define NROW (BDIM * TDIM)   // 32800
#define VTLD 1088            // vT row stride (elements, 16B-aligned)
#define LDP  72              // LDS row stride for attn tiles
#define LDQ  40              // LDS row stride for qkv tiles (BK=32)
#define LDO  200             // Os row stride (elements)
#define NTILES 17

typedef __attribute__((ext_vector_type(8))) short short8v;   // 8 bf16 (4 VGPRs)
typedef __attribute__((ext_vector_type(4))) float f32x4;     // MFMA C/D frag

__device__ __forceinline__ unsigned short f2bf(float f) {
    unsigned int u = __float_as_uint(f);
    u += 0x7FFFu + ((u >> 16) & 1u);      // round-to-nearest-even
    return (unsigned short)(u >> 16);
}

__device__ __forceinline__ short8v pack8(float4 a, float4 b) {
    union { short8v v; unsigned short s[8]; } u;
    u.s[0] = f2bf(a.x); u.s[1] = f2bf(a.y); u.s[2] = f2bf(a.z); u.s[3] = f2bf(a.w);
    u.s[4] = f2bf(b.x); u.s[5] = f2bf(b.y); u.s[6] = f2bf(b.z); u.s[7] = f2bf(b.w);
    return u.v;
}

// Raw workgroup barrier (no vmcnt(0) drain) — attn only.
__device__ __forceinline__ void wg_barrier() {
    asm volatile("s_waitcnt lgkmcnt(0)" ::: "memory");
    __builtin_amdgcn_s_barrier();
    __builtin_amdgcn_sched_barrier(0);
}

// ---- 16-lane DPP reductions (attn only) ----
template<int CTRL>
__device__ __forceinline__ float dpp_f(float x) {
    return __int_as_float(__builtin_amdgcn_update_dpp(
        __float_as_int(x), __float_as_int(x), CTRL, 0xF, 0xF, true));
}
__device__ __forceinline__ float red16_max(float x) {
    x = fmaxf(x, dpp_f<0xB1>(x));
    x = fmaxf(x, dpp_f<0x4E>(x));
    x = fmaxf(x, dpp_f<0x124>(x));
    x = fmaxf(x, dpp_f<0x128>(x));
    return x;
}
__device__ __forceinline__ float red16_sum(float x) {
    x += dpp_f<0xB1>(x);
    x += dpp_f<0x4E>(x);
    x += dpp_f<0x124>(x);
    x += dpp_f<0x128>(x);
    return x;
}

// ---------------------------------------------------------------------------
// Kernel 0: W -> bf16, transposed: wT[c][k], c = 0..191 (q|k|v), k = 0..767
// ---------------------------------------------------------------------------
__global__ __launch_bounds__(256) void prep_w_kernel(
    const float* __restrict__ Wq, const float* __restrict__ Wk,
    const float* __restrict__ Wv, unsigned short* __restrict__ wT)
{
    const int c = blockIdx.x;
    const float* W = (c < 64) ? Wq : (c < 128) ? Wk : Wv;
    const int cc = c & 63;
    for (int k = threadIdx.x; k < DDIM; k += 256)
        wT[(size_t)c * DDIM + k] = f2bf(W[(size_t)k * 64 + cc]);
}

// ---------------------------------------------------------------------------
// Kernel 1: MFMA QKV projection + fused LN + heads. K-loop FROZEN (R12-best).
// New: epilogue stages q/k/v through LDS Os[64][200] and writes them as fully
// coalesced short8v row spans (qb row stride = 128 B -> 1 KB/instr), replacing
// 48 scattered 2-byte stores per thread.
// ---------------------------------------------------------------------------
__global__ __launch_bounds__(256) void qkv_tile_kernel(
    const float* __restrict__ x, const unsigned short* __restrict__ wT,
    const float* __restrict__ gq, const float* __restrict__ bq,
    const float* __restrict__ gk, const float* __restrict__ bk,
    const float* __restrict__ Wsig, const float* __restrict__ bsig,
    const float* __restrict__ Wa, const float* __restrict__ ba,
    unsigned short* __restrict__ qb, unsigned short* __restrict__ kb,
    unsigned short* __restrict__ vb,
    float* __restrict__ a8, float* __restrict__ isx, float* __restrict__ isy)
{
    __shared__ unsigned short As[2][64][LDQ];    // 10.2 KB
    __shared__ unsigned short Bs[2][192][LDQ];   // 30.7 KB
    __shared__ unsigned short Os[64][LDO];       // 25.6 KB (epilogue staging)

    const int t  = threadIdx.x;
    const int wv = t >> 6;
    const int ln = t & 63;
    const int lq = ln >> 4;
    const int lr = ln & 15;
    const int tok0 = blockIdx.x * 64;           // flat row (b*TDIM + ti)

    const int arow = t >> 2;
    const int aseg = t & 3;
    const float* aptr = x + (size_t)min(tok0 + arow, NROW - 1) * DDIM + aseg * 8;
    const int brow = t >> 2;
    const int bseg = t & 3;

    f32x4 acc[12];
#pragma unroll
    for (int ni = 0; ni < 12; ++ni) acc[ni] = (f32x4){0.f, 0.f, 0.f, 0.f};

    float4 ra0, ra1;
    short8v rb0, rb1, rb2;

    ra0 = *(const float4*)(aptr + 0);
    ra1 = *(const float4*)(aptr + 4);
    rb0 = *(const short8v*)&wT[(size_t)(brow +   0) * DDIM + bseg * 8];
    rb1 = *(const short8v*)&wT[(size_t)(brow +  64) * DDIM + bseg * 8];
    rb2 = *(const short8v*)&wT[(size_t)(brow + 128) * DDIM + bseg * 8];

#pragma unroll
    for (int ks = 0; ks < 24; ++ks) {
        const int buf = ks & 1;
        *(short8v*)&As[buf][arow][aseg * 8]        = pack8(ra0, ra1);
        *(short8v*)&Bs[buf][brow +   0][bseg * 8]  = rb0;
        *(short8v*)&Bs[buf][brow +  64][bseg * 8]  = rb1;
        *(short8v*)&Bs[buf][brow + 128][bseg * 8]  = rb2;
        if (ks + 1 < 24) {
            const int k0 = (ks + 1) * 32;
            ra0 = *(const float4*)(aptr + k0 + 0);
            ra1 = *(const float4*)(aptr + k0 + 4);
            rb0 = *(const short8v*)&wT[(size_t)(brow +   0) * DDIM + k0 + bseg * 8];
            rb1 = *(const short8v*)&wT[(size_t)(brow +  64) * DDIM + k0 + bseg * 8];
            rb2 = *(const short8v*)&wT[(size_t)(brow + 128) * DDIM + k0 + bseg * 8];
        }
        __syncthreads();
        short8v af = *(const short8v*)&As[buf][wv * 16 + lr][lq * 8];
#pragma unroll
        for (int ni = 0; ni < 12; ++ni) {
            short8v bf = *(const short8v*)&Bs[buf][16 * ni + lr][lq * 8];
            acc[ni] = __builtin_amdgcn_mfma_f32_16x16x32_bf16(af, bf, acc[ni], 0, 0, 0);
        }
    }

    // ---- epilogue: LN(q), LN(k), alpha/sigma head -> Os, then coalesced ----
    float gqv[4], bqv[4], gkv[4], bkv[4], wav[4], ws0[4], ws1[4];
#pragma unroll
    for (int ni = 0; ni < 4; ++ni) {
        int c = lr + 16 * ni;
        gqv[ni] = gq[c]; bqv[ni] = bq[c];
        gkv[ni] = gk[c]; bkv[ni] = bk[c];
        wav[ni] = Wa[c];
        ws0[ni] = Wsig[2 * c];
        ws1[ni] = Wsig[2 * c + 1];
    }
    const float ba0 = ba[0], bs0 = bsig[0], bs1 = bsig[1];

#pragma unroll
    for (int reg = 0; reg < 4; ++reg) {
        const int rloc = wv * 16 + lq * 4 + reg;   // row within block tile
        const int tokr = tok0 + rloc;

        float s1 = 0.f, s2 = 0.f;
#pragma unroll
        for (int ni = 0; ni < 4; ++ni) {
            float v = acc[ni][reg];
            s1 += v; s2 += v * v;
        }
#pragma unroll
        for (int off = 1; off < 16; off <<= 1) {
            s1 += __shfl_xor(s1, off);
            s2 += __shfl_xor(s2, off);
        }
        float mean = s1 * (1.f / 64.f);
        float var  = s2 * (1.f / 64.f) - mean * mean;
        float rstd = rsqrtf(var + EPSLN);
        float qn[4];
#pragma unroll
        for (int ni = 0; ni < 4; ++ni)
            qn[ni] = (acc[ni][reg] - mean) * rstd * gqv[ni] + bqv[ni];

        s1 = 0.f; s2 = 0.f;
#pragma unroll
        for (int ni = 0; ni < 4; ++ni) {
            float v = acc[4 + ni][reg];
            s1 += v; s2 += v * v;
        }
#pragma unroll
        for (int off = 1; off < 16; off <<= 1) {
            s1 += __shfl_xor(s1, off);
            s2 += __shfl_xor(s2, off);
        }
        mean = s1 * (1.f / 64.f);
        var  = s2 * (1.f / 64.f) - mean * mean;
        rstd = rsqrtf(var + EPSLN);
        float kn[4];
#pragma unroll
        for (int ni = 0; ni < 4; ++ni)
            kn[ni] = (acc[4 + ni][reg] - mean) * rstd * gkv[ni] + bkv[ni];

        float da = 0.f, d0 = 0.f, d1 = 0.f;
#pragma unroll
        for (int ni = 0; ni < 4; ++ni) {
            da += qn[ni] * wav[ni];
            d0 += qn[ni] * ws0[ni];
            d1 += qn[ni] * ws1[ni];
        }
#pragma unroll
        for (int off = 1; off < 16; off <<= 1) {
            da += __shfl_xor(da, off);
            d0 += __shfl_xor(d0, off);
            d1 += __shfl_xor(d1, off);
        }

        // stage to LDS (no guard needed; OOB rows simply never flushed)
#pragma unroll
        for (int ni = 0; ni < 4; ++ni) {
            int c = lr + 16 * ni;
            Os[rloc][c]       = f2bf(qn[ni]);
            Os[rloc][64 + c]  = f2bf(kn[ni]);
            Os[rloc][128 + c] = f2bf(acc[8 + ni][reg]);
        }

        if (tokr < NROW && lr == 0) {
            int bidx = tokr / TDIM;
            int ti   = tokr - bidx * TDIM;
            if (ti >= 1) {
                int p = bidx * TPATCH + ti - 1;
                float av = da + ba0;
                float sp = (av > 20.f) ? av : log1pf(__expf(av));
                a8[p] = sp * (1.f / SCALE);
                float sx = 1.f / (1.f + __expf(-(d0 + bs0)));
                float sy = 1.f / (1.f + __expf(-(d1 + bs1)));
                isx[p] = 0.5f / (sx * sx);
                isy[p] = 0.5f / (sy * sy);
            }
        }
    }

    __syncthreads();   // all waves' Os rows staged

    // cooperative, fully-coalesced flush: 64 lanes = one contiguous 1 KB span
#pragma unroll
    for (int j = 0; j < 2; ++j) {
        int c   = t + 256 * j;        // 0..511
        int row = c >> 3;
        int col = (c & 7) * 8;
        if (tok0 + row < NROW) {
            size_t base = (size_t)(tok0 + row) * 64 + col;
            *(short8v*)&qb[base] = *(const short8v*)&Os[row][col];
            *(short8v*)&kb[base] = *(const short8v*)&Os[row][64 + col];
            *(short8v*)&vb[base] = *(const short8v*)&Os[row][128 + col];
        }
    }
}

// ---------------------------------------------------------------------------
// Kernel 1b: vb [token][dh] -> vT [b][dh][token] via LDS transpose. (R12)
// ---------------------------------------------------------------------------
__global__ __launch_bounds__(256) void vtrans_kernel(
    const unsigned short* __restrict__ vb, unsigned short* __restrict__ vT)
{
    __shared__ unsigned short tile[64][LDP];   // [dh][token]
    const int t  = threadIdx.x;
    const int bb = blockIdx.y;
    const int t0 = blockIdx.x * 64;

#pragma unroll
    for (int it = 0; it < 2; ++it) {
        int lin = t + it * 256;
        int tok = lin >> 3;
        int d0  = (lin & 7) * 8;
        short8v v8 = {0, 0, 0, 0, 0, 0, 0, 0};
        if (t0 + tok < TDIM)
            v8 = *(const short8v*)&vb[((size_t)bb * TDIM + t0 + tok) * 64 + d0];
        union { short8v v; unsigned short s[8]; } u; u.v = v8;
#pragma unroll
        for (int j = 0; j < 8; ++j) tile[d0 + j][tok] = u.s[j];
    }
    __syncthreads();

    const int dh = t >> 2;
    const int ch = t & 3;
    short8v o0 = *(const short8v*)&tile[dh][ch * 16];
    short8v o1 = *(const short8v*)&tile[dh][ch * 16 + 8];
    size_t dst = ((size_t)bb * 64 + dh) * VTLD + t0 + ch * 16;
    *(short8v*)&vT[dst]     = o0;
    *(short8v*)&vT[dst + 8] = o1;
}

// ---------------------------------------------------------------------------
// Kernel 2: MFMA flash attention — R12-measured-best (QBLK=64, 544 blocks,
// raw barriers, dbuf K/V, issue-early/write-late, DPP softmax). Reverted.
// ---------------------------------------------------------------------------
__global__ __launch_bounds__(256) void attn_mfma_kernel(
    const unsigned short* __restrict__ qb, const unsigned short* __restrict__ kb,
    const unsigned short* __restrict__ vT,
    const float* __restrict__ a8, const float* __restrict__ isx,
    const float* __restrict__ isy, float* __restrict__ out)
{
    __shared__ unsigned short Ks[2][64][LDP];
    __shared__ unsigned short Vt[2][64][LDP];   // [dh][key]
    __shared__ unsigned short Pt[4][16][LDP];   // per-wave [q][key]

    const int t  = threadIdx.x;
    const int wv = t >> 6;
    const int ln = t & 63;
    const int lq = ln >> 4;
    const int lr = ln & 15;
    const int bb = blockIdx.y;
    const int q0 = blockIdx.x * 64;

    const int qrow = min(q0 + wv * 16 + lr, TDIM - 1);
    const size_t qbase = ((size_t)bb * TDIM + qrow) * 64;
    const short8v aq0 = *(const short8v*)&qb[qbase + lq * 8];
    const short8v aq1 = *(const short8v*)&qb[qbase + 32 + lq * 8];

    float a8q[4], sxq[4], syq[4], qpy[4], qpx[4];
    bool  hasS[4];
#pragma unroll
    for (int reg = 0; reg < 4; ++reg) {
        int qg = q0 + wv * 16 + lq * 4 + reg;
        hasS[reg] = false;
        a8q[reg] = 0.f; sxq[reg] = 0.f; syq[reg] = 0.f; qpy[reg] = 0.f; qpx[reg] = 0.f;
        if (qg >= 1 && qg < TDIM) {
            int qp = qg - 1;
            hasS[reg] = true;
            a8q[reg] = a8 [bb * TPATCH + qp];
            sxq[reg] = isx[bb * TPATCH + qp];
            syq[reg] = isy[bb * TPATCH + qp];
            qpy[reg] = (float)(qp >> 5);
            qpx[reg] = (float)(qp & 31);
        }
    }

    float m[4]  = {-1e30f, -1e30f, -1e30f, -1e30f};
    float l[4]  = {0.f, 0.f, 0.f, 0.f};
    f32x4 oacc[4];
#pragma unroll
    for (int ni = 0; ni < 4; ++ni) oacc[ni] = (f32x4){0.f, 0.f, 0.f, 0.f};

    const int sk_row = t >> 3;
    const int sk_d0  = (t & 7) * 8;
    short8v rk[2], rv[2];

#define ALOAD(KT0)                                                             \
    do {                                                                       \
        _Pragma("unroll") for (int it = 0; it < 2; ++it) {                     \
            int key = sk_row + 32 * it;                                        \
            int kg  = (KT0) + key;                                             \
            rk[it] = (kg < TDIM)                                               \
                ? *(const short8v*)&kb[((size_t)bb * TDIM + kg) * 64 + sk_d0]  \
                : (short8v){0, 0, 0, 0, 0, 0, 0, 0};                           \
            rv[it] = *(const short8v*)&vT[((size_t)bb * 64 + key) * VTLD +     \
                                          (KT0) + sk_d0];                      \
        }                                                                      \
    } while (0)

#define ASTORE(BUF)                                                            \
    do {                                                                       \
        _Pragma("unroll") for (int it = 0; it < 2; ++it) {                     \
            *(short8v*)&Ks[BUF][sk_row + 32 * it][sk_d0] = rk[it];             \
            *(short8v*)&Vt[BUF][sk_row + 32 * it][sk_d0] = rv[it];             \
        }                                                                      \
    } while (0)

    ALOAD(0);
    ASTORE(0);
    wg_barrier();

    for (int tile = 0; tile < NTILES; ++tile) {
        const int kt0 = tile * 64;
        const int buf = tile & 1;
        if (tile + 1 < NTILES) ALOAD(kt0 + 64);

        f32x4 sac[4];
#pragma unroll
        for (int ni = 0; ni < 4; ++ni) sac[ni] = (f32x4){0.f, 0.f, 0.f, 0.f};
#pragma unroll
        for (int ni = 0; ni < 4; ++ni) {
            short8v b0 = *(const short8v*)&Ks[buf][16 * ni + lr][lq * 8];
            short8v b1 = *(const short8v*)&Ks[buf][16 * ni + lr][32 + lq * 8];
            sac[ni] = __builtin_amdgcn_mfma_f32_16x16x32_bf16(aq0, b0, sac[ni], 0, 0, 0);
            sac[ni] = __builtin_amdgcn_mfma_f32_16x16x32_bf16(aq1, b1, sac[ni], 0, 0, 0);
        }

#pragma unroll
        for (int ni = 0; ni < 4; ++ni) {
            int key = kt0 + 16 * ni + lr;
            int kp  = key - 1;
            float ky = (float)(kp >> 5);
            float kx = (float)(kp & 31);
            bool kvalid = (key >= 1) && (key < TDIM);
#pragma unroll
            for (int reg = 0; reg < 4; ++reg) {
                float z = sac[ni][reg] * (1.f / SCALE);
                if (kvalid && hasS[reg]) {
                    float dy = qpy[reg] - ky;
                    float dx = qpx[reg] - kx;
                    z += a8q[reg] * __expf(-(dx * dx * sxq[reg] + dy * dy * syq[reg]));
                }
                if (key >= TDIM) z = -1e30f;
                sac[ni][reg] = z;
            }
        }

        float scf[4];
#pragma unroll
        for (int reg = 0; reg < 4; ++reg) {
            float mx = fmaxf(fmaxf(sac[0][reg], sac[1][reg]),
                             fmaxf(sac[2][reg], sac[3][reg]));
            mx = red16_max(mx);
            float mn = fmaxf(m[reg], mx);
            scf[reg] = __expf(m[reg] - mn);
            m[reg] = mn;
            float ts = 0.f;
#pragma unroll
            for (int ni = 0; ni < 4; ++ni) {
                float pp = __expf(sac[ni][reg] - mn);
                sac[ni][reg] = pp;
                ts += pp;
            }
            ts = red16_sum(ts);
            l[reg] = l[reg] * scf[reg] + ts;
        }
#pragma unroll
        for (int ni = 0; ni < 4; ++ni)
#pragma unroll
            for (int reg = 0; reg < 4; ++reg)
                oacc[ni][reg] *= scf[reg];

#pragma unroll
        for (int ni = 0; ni < 4; ++ni)
#pragma unroll
            for (int reg = 0; reg < 4; ++reg)
                Pt[wv][lq * 4 + reg][16 * ni + lr] = f2bf(sac[ni][reg]);

#pragma unroll
        for (int ks = 0; ks < 2; ++ks) {
            short8v pa = *(const short8v*)&Pt[wv][lr][ks * 32 + lq * 8];
#pragma unroll
            for (int ni = 0; ni < 4; ++ni) {
                short8v bv = *(const short8v*)&Vt[buf][16 * ni + lr][ks * 32 + lq * 8];
                oacc[ni] = __builtin_amdgcn_mfma_f32_16x16x32_bf16(pa, bv, oacc[ni], 0, 0, 0);
            }
        }

        if (tile + 1 < NTILES) ASTORE(buf ^ 1);
        wg_barrier();
    }
#undef ALOAD
#undef ASTORE

#pragma unroll
    for (int reg = 0; reg < 4; ++reg) {
        int qg = q0 + wv * 16 + lq * 4 + reg;
        if (qg < TDIM) {
            float rl = 1.f / l[reg];
#pragma unroll
            for (int ni = 0; ni < 4; ++ni)
                out[((size_t)bb * TDIM + qg) * 64 + 16 * ni + lr] = oacc[ni][reg] * rl;
        }
    }
}

extern "C" void kernel_launch(void* const* d_in, const int* in_sizes, int n_in,
                              void* d_out, int out_size, void* d_ws, size_t ws_size,
                              hipStream_t stream)
{
    const float* x    = (const float*)d_in[0];
    const float* Wq   = (const float*)d_in[1];
    const float* Wk   = (const float*)d_in[2];
    const float* Wv   = (const float*)d_in[3];
    const float* gq   = (const float*)d_in[4];
    const float* bq   = (const float*)d_in[5];
    const float* gk   = (const float*)d_in[6];
    const float* bk   = (const float*)d_in[7];
    const float* Wsig = (const float*)d_in[8];
    const float* bsig = (const float*)d_in[9];
    const float* Wa   = (const float*)d_in[10];
    const float* ba   = (const float*)d_in[11];
    float* out = (float*)d_out;

    // ---- workspace layout ----
    char* w = (char*)d_ws;
    const size_t NQ = (size_t)NROW * 64;
    unsigned short* qb = (unsigned short*)w;   w += NQ * 2;
    unsigned short* kb = (unsigned short*)w;   w += NQ * 2;
    unsigned short* vb = (unsigned short*)w;   w += NQ * 2;
    unsigned short* vT = (unsigned short*)w;   w += (size_t)BDIM * 64 * VTLD * 2;
    float* a8  = (float*)w;                    w += (size_t)BDIM * TPATCH * 4;
    float* isx = (float*)w;                    w += (size_t)BDIM * TPATCH * 4;
    float* isy = (float*)w;                    w += (size_t)BDIM * TPATCH * 4;
    unsigned short* wT = (unsigned short*)w;   w += (size_t)192 * DDIM * 2;

    hipLaunchKernelGGL(prep_w_kernel, dim3(192), dim3(256), 0, stream,
                       Wq, Wk, Wv, wT);

    const int nblk1 = (NROW + 63) / 64;   // 513
    hipLaunchKernelGGL(qkv_tile_kernel, dim3(nblk1), dim3(256), 0, stream,
                       x, wT, gq, bq, gk, bk, Wsig, bsig, Wa, ba,
                       qb, kb, vb, a8, isx, isy);

    hipLaunchKernelGGL(vtrans_kernel, dim3(17, BDIM), dim3(256), 0, stream,
                       vb, vT);

    hipLaunchKernelGGL(attn_mfma_kernel, dim3(17, BDIM), dim3(256), 0, stream,
                       qb, kb, vT, a8, isx, isy, out);
}